// Round 6
// baseline (181.605 us; speedup 1.0000x reference)
//
#include <hip/hip_runtime.h>

typedef float f32x4 __attribute__((ext_vector_type(4)));

#define N_TOKENS 131072
#define D_MODEL  512
#define PATHS    16
#define CAP      16384            // CAP_FACTOR * N / P
#define TPB      256
#define NBLK     (N_TOKENS / TPB) // 512 token blocks
#define F4_ROW   (D_MODEL / 4)    // 128 f32x4 per row
#define ROWS_TOTAL (PATHS * CAP)  // 262144
#define R_PER_WG 64               // rows per fill workgroup
#define FILL_WGS (ROWS_TOTAL / R_PER_WG) // 4096

// ---------------------------------------------------------------------------
// Kernel 1: per-token argmax (first-max wins) + stable rank within block +
// per-block per-path histogram.
// ---------------------------------------------------------------------------
__global__ void k_argmax_hist(const float* __restrict__ score,
                              int* __restrict__ packed,
                              int* __restrict__ blkcnt) {
    __shared__ int wcount[TPB / 64][PATHS];
    const int t    = blockIdx.x * TPB + threadIdx.x;
    const int lane = threadIdx.x & 63;
    const int wid  = threadIdx.x >> 6;

    const f32x4* s4 = reinterpret_cast<const f32x4*>(score) + (size_t)t * 4;
    f32x4 a = s4[0], b = s4[1], c = s4[2], d = s4[3];
    float v[16] = {a.x, a.y, a.z, a.w, b.x, b.y, b.z, b.w,
                   c.x, c.y, c.z, c.w, d.x, d.y, d.z, d.w};
    int   myp  = 0;
    float best = v[0];
#pragma unroll
    for (int p = 1; p < 16; ++p) {
        if (v[p] > best) { best = v[p]; myp = p; }   // strict > == first occurrence
    }

    unsigned long long mymask = 0ULL;
#pragma unroll
    for (int p = 0; p < PATHS; ++p) {
        unsigned long long m = __ballot(myp == p);
        if (p == myp) mymask = m;
        if (lane == p) wcount[wid][p] = __popcll(m);
    }
    const int rank_w = __popcll(mymask & ((1ULL << lane) - 1ULL));
    __syncthreads();

    int prefix = 0;
    for (int w = 0; w < wid; ++w) prefix += wcount[w][myp];
    packed[t] = (myp << 16) | (prefix + rank_w);

    if (threadIdx.x < PATHS) {
        int s = 0;
#pragma unroll
        for (int w = 0; w < TPB / 64; ++w) s += wcount[w][threadIdx.x];
        blkcnt[blockIdx.x * PATHS + threadIdx.x] = s;
    }
}

// ---------------------------------------------------------------------------
// Kernel 2: parallel two-level exclusive scan of blkcnt (per path).
// 256 threads: thread = (chunk c = tid>>4, path p = tid&15); 32 blocks/chunk.
// ---------------------------------------------------------------------------
__global__ void k_scan(int* __restrict__ blkcnt, int* __restrict__ cnt) {
    __shared__ int part[16][PATHS + 1];
    const int p = threadIdx.x & 15;
    const int c = threadIdx.x >> 4;
    const int base = c * 32;

    int local[32];
#pragma unroll
    for (int b = 0; b < 32; ++b) local[b] = blkcnt[(base + b) * PATHS + p];
    int s = 0;
#pragma unroll
    for (int b = 0; b < 32; ++b) { int v = local[b]; local[b] = s; s += v; }
    part[c][p] = s;
    __syncthreads();

    if (threadIdx.x < PATHS) {
        int run = 0;
#pragma unroll
        for (int ch = 0; ch < 16; ++ch) {
            int v = part[ch][threadIdx.x];
            part[ch][threadIdx.x] = run;
            run += v;
        }
        cnt[threadIdx.x] = run;
    }
    __syncthreads();

    const int off = part[c][p];
#pragma unroll
    for (int b = 0; b < 32; ++b) blkcnt[(base + b) * PATHS + p] = local[b] + off;
}

// ---------------------------------------------------------------------------
// Kernel 3: slot_token[p*CAP + pos] = token id (inverse permutation).
// ---------------------------------------------------------------------------
__global__ void k_slots(const int* __restrict__ packed,
                        const int* __restrict__ blkoff,
                        int* __restrict__ slot_token) {
    const int t  = blockIdx.x * TPB + threadIdx.x;
    const int pk = packed[t];
    const int p  = pk >> 16;
    const int r  = pk & 0xffff;
    const int pos = blkoff[blockIdx.x * PATHS + p] + r;
    if (pos < CAP) slot_token[p * CAP + pos] = t;
}

// ---------------------------------------------------------------------------
// Kernel 4: fill. Each wg owns 64 contiguous output rows of one path.
// Wave-per-row: each of the 4 waves owns an independent row stream; each lane
// issues two 16B loads per row (cols lane, lane+64) -> with unroll 4, 8 loads
// in flight per lane. Loads nontemporal (read-once, don't pollute L2);
// stores PLAIN so L2 write-combining handles the 512 MB stream.
// ---------------------------------------------------------------------------
__global__ void k_fill(const f32x4* __restrict__ inputs,
                       const int* __restrict__ slot_token,
                       const int* __restrict__ cnt,
                       f32x4* __restrict__ out) {
    __shared__ int toks[R_PER_WG];
    const int row0 = blockIdx.x * R_PER_WG;
    const int p    = row0 >> 14;               // CAP = 2^14
    const int cp   = cnt[p];
    if (threadIdx.x < R_PER_WG)
        toks[threadIdx.x] = slot_token[row0 + threadIdx.x];
    __syncthreads();

    const int lane = threadIdx.x & 63;
    const int wid  = threadIdx.x >> 6;         // 0..3: wave-private row stream
    const int jrel = row0 & (CAP - 1);
    int ndata = cp - jrel;
    ndata = ndata < 0 ? 0 : (ndata > R_PER_WG ? R_PER_WG : ndata);

    // data rows: gather (one row per wave per iteration, 2 loads per lane)
#pragma unroll 4
    for (int r = wid; r < ndata; r += 4) {
        const size_t ib = (size_t)toks[r] * F4_ROW;
        const f32x4 v0 = __builtin_nontemporal_load(&inputs[ib + lane]);
        const f32x4 v1 = __builtin_nontemporal_load(&inputs[ib + 64 + lane]);
        const size_t ob = (size_t)(row0 + r) * F4_ROW;
        out[ob + lane]      = v0;
        out[ob + 64 + lane] = v1;
    }

    // zero rows: branch-free contiguous tail (plain stores)
    const f32x4 z = {0.f, 0.f, 0.f, 0.f};
#pragma unroll 4
    for (int rz = ndata + ((wid - ndata) & 3); rz < R_PER_WG; rz += 4) {
        const size_t ob = (size_t)(row0 + rz) * F4_ROW;
        out[ob + lane]      = z;
        out[ob + 64 + lane] = z;
    }
}

// ---------------------------------------------------------------------------
extern "C" void kernel_launch(void* const* d_in, const int* in_sizes, int n_in,
                              void* d_out, int out_size, void* d_ws, size_t ws_size,
                              hipStream_t stream) {
    const float* inputs = (const float*)d_in[0];
    const float* score  = (const float*)d_in[1];
    float*       out    = (float*)d_out;

    // Workspace (ints): packed[N] | blkcnt[NBLK*P] | cnt[P] | slot_token[P*CAP]
    int* w          = (int*)d_ws;
    int* packed     = w;
    int* blkcnt     = packed + N_TOKENS;
    int* cnt        = blkcnt + NBLK * PATHS;
    int* slot_token = cnt + PATHS;

    k_argmax_hist<<<NBLK, TPB, 0, stream>>>(score, packed, blkcnt);
    k_scan<<<1, TPB, 0, stream>>>(blkcnt, cnt);
    k_slots<<<NBLK, TPB, 0, stream>>>(packed, blkcnt, slot_token);
    k_fill<<<FILL_WGS, TPB, 0, stream>>>(
        (const f32x4*)inputs, slot_token, cnt, (f32x4*)out);
}